// Round 4
// baseline (658.658 us; speedup 1.0000x reference)
//
#include <hip/hip_runtime.h>
#include <hip/hip_bf16.h>
#include <hip/hip_cooperative_groups.h>
#include <float.h>
#include <math.h>

namespace cg = cooperative_groups;

// Problem dims (fixed by reference)
constexpr int B  = 4;
constexpr int D  = 512;
constexpr int C  = 2;
constexpr int Dc = 256;     // D / C
constexpr int FT = 256 * 256;   // 65536
constexpr int HW = 14 * 14;     // 196
constexpr int OUTC = 2 * Dc + D;  // 1024 output channels
constexpr float EPSV = 1e-8f;

typedef float f4 __attribute__((ext_vector_type(4)));

// ---------------- fused cooperative kernel ----------------
// ws layout (floats):
//   xp   @ 0      : 2048         xp[b*C*Dc + c*Dc + dc]
//   pd0  @ 2048   : 32*256       partial dots (own xp)
//   pd1  @ 10240  : 32*256       partial dots (other xp)
//   pvs  @ 18432  : 32*256       partial v-sq-norms
//   maps @ 26624  : 3136         maps[b][p][c][hw]  (row = b*4+p*2+c)
//   mind @ 29760  : 8 ints
__global__ __launch_bounds__(256, 4) void k_fused(const float* __restrict__ x,
                                                  const float* __restrict__ v0,
                                                  const float* __restrict__ v1,
                                                  float* __restrict__ out,
                                                  float* __restrict__ ws) {
    cg::grid_group grid = cg::this_grid();
    const int tid = threadIdx.x;
    const int blk = blockIdx.x;   // 0..1023

    float* xp   = ws;
    float* pd0  = ws + 2048;
    float* pd1  = ws + 10240;
    float* pvs  = ws + 18432;
    float* maps = ws + 26624;
    int*   mind = (int*)(ws + 29760);

    __shared__ float sm[4];
    __shared__ float s_xn[8];
    __shared__ float s_mx[16];
    __shared__ int   s_ai[16];
    __shared__ int   s_pb[B];
    __shared__ float cand_v[256];
    __shared__ int   cand_i[256];

    // ---- Phase 1: max-reduce over (F,T) + copy x -> out[:, 2*Dc + d]; 2 slices/block
    for (int s = 0; s < 2; ++s) {
        const int slice = blk * 2 + s;           // b*D + d
        const int b = slice / D, d = slice % D;
        const f4* xs = (const f4*)(x + (size_t)slice * FT);
        f4* os = (f4*)(out + ((size_t)(b * OUTC + 2 * Dc + d)) * FT);
        float m = -FLT_MAX;
        for (int i0 = tid; i0 < FT / 4; i0 += 256 * 8) {
            f4 v[8];
            #pragma unroll
            for (int u = 0; u < 8; ++u)
                v[u] = __builtin_nontemporal_load(&xs[i0 + u * 256]);
            #pragma unroll
            for (int u = 0; u < 8; ++u) {
                __builtin_nontemporal_store(v[u], &os[i0 + u * 256]);
                m = fmaxf(m, fmaxf(fmaxf(v[u].x, v[u].y), fmaxf(v[u].z, v[u].w)));
            }
        }
        for (int off = 32; off; off >>= 1) m = fmaxf(m, __shfl_down(m, off, 64));
        if ((tid & 63) == 0) sm[tid >> 6] = m;
        __syncthreads();
        if (tid == 0) xp[slice] = fmaxf(fmaxf(sm[0], sm[1]), fmaxf(sm[2], sm[3]));
        __syncthreads();
    }
    grid.sync();

    // ---- Phase 2: partial dot products, blocks 0..31 = (b, c, dc-quarter)
    if (blk < 32) {
        const int b = blk >> 3, c = (blk >> 2) & 1, q = blk & 3;
        if (tid < HW) {
            const float* vv = (c == 0 ? v0 : v1) + (size_t)b * Dc * HW;
            const float* xc = xp + (b * C + c) * Dc;
            const float* xo = xp + (b * C + (1 - c)) * Dc;
            float d0 = 0.f, d1 = 0.f, vs = 0.f;
            for (int dc = q * 64; dc < q * 64 + 64; ++dc) {
                float v = vv[dc * HW + tid];
                d0 = fmaf(xc[dc], v, d0);
                d1 = fmaf(xo[dc], v, d1);
                vs = fmaf(v, v, vs);
            }
            pd0[blk * 256 + tid] = d0;
            pd1[blk * 256 + tid] = d1;
            pvs[blk * 256 + tid] = vs;
        }
    }
    grid.sync();

    // ---- Phase 3: block 0 combines everything (tiny)
    if (blk == 0) {
        // norms of xp[b,c,:] — 8 groups of 32 lanes
        {
            const int g = tid >> 5, l = tid & 31;
            float acc = 0.f;
            for (int dc = l; dc < Dc; dc += 32) {
                float v = xp[g * Dc + dc];
                acc = fmaf(v, v, acc);
            }
            for (int off = 16; off; off >>= 1) acc += __shfl_down(acc, off, 32);
            if (l == 0) s_xn[g] = sqrtf(acc);
        }
        __syncthreads();
        // maps[b][p][c][hw]
        for (int i = tid; i < 16 * HW; i += 256) {
            const int row = i / HW;           // b*4 + p*2 + c
            const int hw = i % HW;
            const int b = row >> 2, p = (row >> 1) & 1, c = row & 1;
            const int base = b * 8 + c * 4;
            float d = 0.f, vs = 0.f;
            for (int q = 0; q < 4; ++q) {
                const int o = (base + q) * 256 + hw;
                d += (p == 0 ? pd0[o] : pd1[o]);
                vs += pvs[o];
            }
            const float xn = (p == 0) ? s_xn[b * C + c] : s_xn[b * C + (1 - c)];
            maps[i] = d / fmaxf(xn * sqrtf(vs), EPSV);
        }
        __syncthreads();
        // max + first-index argmax per row (16 rows × 196), 16 threads/row
        {
            const int row = tid >> 4, sub = tid & 15;
            float bv = -FLT_MAX; int bi = HW;
            for (int hw = sub; hw < HW; hw += 16) {
                float v = maps[row * HW + hw];
                if (v > bv) { bv = v; bi = hw; }
            }
            cand_v[tid] = bv; cand_i[tid] = bi;
            __syncthreads();
            if (sub == 0) {
                float mv = -FLT_MAX; int mi = 0;
                for (int k = 0; k < 16; ++k) {
                    float v = cand_v[row * 16 + k]; int idx = cand_i[row * 16 + k];
                    if (v > mv || (v == mv && idx < mi)) { mv = v; mi = idx; }
                }
                s_mx[row] = mv; s_ai[row] = mi;
            }
        }
        __syncthreads();
        if (tid == 0) {
            float L = 0.f;
            for (int b = 0; b < B; ++b) {
                const float s0 = s_mx[b * 4 + 0] + s_mx[b * 4 + 1];
                const float s1 = s_mx[b * 4 + 2] + s_mx[b * 4 + 3];
                const int p = (s1 > s0) ? 1 : 0;   // stable argsort(-scores): tie -> p=0
                s_pb[b] = p;
                L += p ? (s0 - s1) : (s1 - s0);
            }
            out[(size_t)B * OUTC * FT] = L / (float)B;
        }
        __syncthreads();
        const size_t att_off = (size_t)B * OUTC * FT + 1;
        for (int i = tid; i < B * C * HW; i += 256) {
            const int b = i / (C * HW);
            const int r = i % (C * HW);
            const int c = r / HW, hw = r % HW;
            out[att_off + i] = maps[(b * 4 + s_pb[b] * 2 + c) * HW + hw];
        }
        if (tid < B * C) {
            const int b = tid / C, c = tid % C;
            mind[tid] = s_ai[b * 4 + s_pb[b] * 2 + c];
        }
    }
    grid.sync();

    // ---- Phase 4: broadcast-fill out[:, 0:2*Dc]; 2 FULL slices per block
    // (2048 fill slices = B * 2*Dc; R3 bug was covering only 512 of them)
    for (int s = 0; s < 2; ++s) {
        const int slice = blk * 2 + s;     // 0..2047 = b*(2*Dc) + r
        const int b = slice / (2 * Dc);
        const int r = slice % (2 * Dc);
        const int c = r / Dc, dc = r % Dc;
        const int hw = mind[b * C + c];
        const float* vv = (c == 0 ? v0 : v1);
        const float val = vv[((size_t)(b * Dc + dc)) * HW + hw];
        f4 v4 = {val, val, val, val};
        f4* os = (f4*)(out + ((size_t)(b * OUTC + c * Dc + dc)) * FT);
        for (int i0 = tid; i0 < FT / 4; i0 += 256 * 8) {
            #pragma unroll
            for (int u = 0; u < 8; ++u)
                __builtin_nontemporal_store(v4, &os[i0 + u * 256]);
        }
    }
}

// ---------------- fallback path (proven R2 kernels) ----------------
__global__ __launch_bounds__(256) void kA_maxcopy(const float* __restrict__ x,
                                                  float* __restrict__ out,
                                                  float* __restrict__ xp) {
    const int slice = blockIdx.x;
    const int b = slice / D;
    const int d = slice % D;
    const f4* xs = (const f4*)(x + (size_t)slice * FT);
    f4* os = (f4*)(out + ((size_t)(b * OUTC + 2 * Dc + d)) * FT);
    float m = -FLT_MAX;
    for (int i0 = threadIdx.x; i0 < FT / 4; i0 += 256 * 8) {
        f4 v[8];
        #pragma unroll
        for (int u = 0; u < 8; ++u)
            v[u] = __builtin_nontemporal_load(&xs[i0 + u * 256]);
        #pragma unroll
        for (int u = 0; u < 8; ++u) {
            __builtin_nontemporal_store(v[u], &os[i0 + u * 256]);
            m = fmaxf(m, fmaxf(fmaxf(v[u].x, v[u].y), fmaxf(v[u].z, v[u].w)));
        }
    }
    for (int off = 32; off; off >>= 1) m = fmaxf(m, __shfl_down(m, off, 64));
    __shared__ float sm[4];
    if ((threadIdx.x & 63) == 0) sm[threadIdx.x >> 6] = m;
    __syncthreads();
    if (threadIdx.x == 0) {
        xp[slice] = fmaxf(fmaxf(sm[0], sm[1]), fmaxf(sm[2], sm[3]));
    }
}

__global__ __launch_bounds__(256) void kB_maps(const float* __restrict__ v0,
                                               const float* __restrict__ v1,
                                               const float* __restrict__ xp,
                                               float* __restrict__ maps,
                                               float* __restrict__ mx,
                                               int* __restrict__ amax) {
    const int bc = blockIdx.x;
    const int b = bc / C, c = bc % C;
    const int tid = threadIdx.x;

    __shared__ float sxc[Dc], sxo[Dc];
    sxc[tid] = xp[(b * C + c) * Dc + tid];
    sxo[tid] = xp[(b * C + (1 - c)) * Dc + tid];
    __syncthreads();

    float ec = sxc[tid] * sxc[tid];
    float eo = sxo[tid] * sxo[tid];
    for (int off = 32; off; off >>= 1) {
        ec += __shfl_down(ec, off, 64);
        eo += __shfl_down(eo, off, 64);
    }
    __shared__ float red[8];
    const int lane = tid & 63, wid = tid >> 6;
    if (lane == 0) { red[wid] = ec; red[4 + wid] = eo; }
    __syncthreads();
    __shared__ float s_xn_c, s_xn_o;
    if (tid == 0) {
        s_xn_c = sqrtf(red[0] + red[1] + red[2] + red[3]);
        s_xn_o = sqrtf(red[4] + red[5] + red[6] + red[7]);
    }
    __syncthreads();
    const float xn_c = s_xn_c, xn_o = s_xn_o;

    float map0 = -FLT_MAX, map1 = -FLT_MAX;
    if (tid < HW) {
        const float* vv = (c == 0 ? v0 : v1) + (size_t)b * Dc * HW;
        float d0 = 0.f, d1 = 0.f, vs = 0.f;
        for (int dc = 0; dc < Dc; ++dc) {
            float v = vv[dc * HW + tid];
            d0 = fmaf(sxc[dc], v, d0);
            d1 = fmaf(sxo[dc], v, d1);
            vs = fmaf(v, v, vs);
        }
        float vn = sqrtf(vs);
        map0 = d0 / fmaxf(xn_c * vn, EPSV);
        map1 = d1 / fmaxf(xn_o * vn, EPSV);
        maps[((b * 2 + 0) * C + c) * HW + tid] = map0;
        maps[((b * 2 + 1) * C + c) * HW + tid] = map1;
    }

    __shared__ float rv[256];
    __shared__ int ri[256];
    for (int p = 0; p < 2; ++p) {
        __syncthreads();
        rv[tid] = (tid < HW) ? (p == 0 ? map0 : map1) : -FLT_MAX;
        ri[tid] = tid;
        __syncthreads();
        for (int s = 128; s; s >>= 1) {
            if (tid < s) {
                float v2 = rv[tid + s]; int i2 = ri[tid + s];
                if (v2 > rv[tid] || (v2 == rv[tid] && i2 < ri[tid])) {
                    rv[tid] = v2; ri[tid] = i2;
                }
            }
            __syncthreads();
        }
        if (tid == 0) {
            mx[(b * 2 + p) * C + c] = rv[0];
            amax[(b * 2 + p) * C + c] = ri[0];
        }
    }
}

__global__ __launch_bounds__(256) void kC_select(const float* __restrict__ maps,
                                                 const float* __restrict__ mx,
                                                 const int* __restrict__ amax,
                                                 float* __restrict__ out,
                                                 int* __restrict__ mind) {
    __shared__ int pbest[B];
    const int tid = threadIdx.x;
    if (tid == 0) {
        float L = 0.f;
        for (int b = 0; b < B; ++b) {
            float s0 = mx[(b * 2 + 0) * C + 0] + mx[(b * 2 + 0) * C + 1];
            float s1 = mx[(b * 2 + 1) * C + 0] + mx[(b * 2 + 1) * C + 1];
            int p = (s1 > s0) ? 1 : 0;
            pbest[b] = p;
            L += p ? (s0 - s1) : (s1 - s0);
        }
        out[(size_t)B * OUTC * FT] = L / (float)B;
    }
    __syncthreads();
    const size_t att_off = (size_t)B * OUTC * FT + 1;
    for (int i = tid; i < B * C * HW; i += blockDim.x) {
        int b = i / (C * HW);
        int r = i % (C * HW);
        int c = r / HW;
        int hw = r % HW;
        out[att_off + i] = maps[((b * 2 + pbest[b]) * C + c) * HW + hw];
    }
    if (tid < B * C) {
        int b = tid / C, c = tid % C;
        mind[tid] = amax[(b * 2 + pbest[b]) * C + c];
    }
}

__global__ __launch_bounds__(256) void kD_fill(const float* __restrict__ v0,
                                               const float* __restrict__ v1,
                                               const int* __restrict__ mind,
                                               float* __restrict__ out) {
    const int n = blockIdx.x;
    const int b = n / (2 * Dc);
    const int r = n % (2 * Dc);
    const int c = r / Dc;
    const int dc = r % Dc;
    const int hw = mind[b * C + c];
    const float* vv = (c == 0 ? v0 : v1);
    const float val = vv[((size_t)(b * Dc + dc)) * HW + hw];
    f4 v4 = {val, val, val, val};
    f4* os = (f4*)(out + ((size_t)(b * OUTC + c * Dc + dc)) * FT);
    for (int i0 = threadIdx.x; i0 < FT / 4; i0 += 256 * 8) {
        #pragma unroll
        for (int u = 0; u < 8; ++u)
            __builtin_nontemporal_store(v4, &os[i0 + u * 256]);
    }
}

extern "C" void kernel_launch(void* const* d_in, const int* in_sizes, int n_in,
                              void* d_out, int out_size, void* d_ws, size_t ws_size,
                              hipStream_t stream) {
    const float* x  = (const float*)d_in[0];
    const float* v0 = (const float*)d_in[1];
    const float* v1 = (const float*)d_in[2];
    float* out = (float*)d_out;
    float* ws = (float*)d_ws;

    void* args[] = {(void*)&x, (void*)&v0, (void*)&v1, (void*)&out, (void*)&ws};
    hipError_t err = hipLaunchCooperativeKernel((const void*)k_fused,
                                                dim3(1024), dim3(256),
                                                args, 0, stream);
    if (err != hipSuccess) {
        // fallback: proven 4-kernel path (distinct ws offsets from fused path
        // don't matter — only one path runs)
        float* xp   = ws;                 // 2048
        float* maps = ws + 2048;          // 3136
        float* mx   = ws + 5184;          // 16
        int*   amax = (int*)(ws + 5200);  // 16
        int*   mind = (int*)(ws + 5216);  // 8
        kA_maxcopy<<<B * D, 256, 0, stream>>>(x, out, xp);
        kB_maps<<<B * C, 256, 0, stream>>>(v0, v1, xp, maps, mx, amax);
        kC_select<<<1, 256, 0, stream>>>(maps, mx, amax, out, mind);
        kD_fill<<<B * 2 * Dc, 256, 0, stream>>>(v0, v1, mind, out);
    }
}

// Round 5
// 317.829 us; speedup vs baseline: 2.0724x; 2.0724x over previous
//
#include <hip/hip_runtime.h>
#include <hip/hip_bf16.h>
#include <float.h>
#include <math.h>

// Problem dims (fixed by reference)
constexpr int B  = 4;
constexpr int D  = 512;
constexpr int C  = 2;
constexpr int Dc = 256;     // D / C
constexpr int FT = 256 * 256;   // 65536
constexpr int HW = 14 * 14;     // 196
constexpr int OUTC = 2 * Dc + D;  // 1024 output channels
constexpr float EPSV = 1e-8f;

typedef float f4 __attribute__((ext_vector_type(4)));

// Workspace layout (floats):
//   xp    @ 0      : B*D   = 2048
//   maps  @ 2048   : B*2*C*HW = 3136
//   mx    @ 5184   : B*2*C = 16
//   amax  @ 5200   : 16 (int)
//   mind  @ 5216   : 8  (int)

// Kernel A: fused max-reduce over (F,T) + copy x -> out[:, 2*Dc + d]
// NT loads (single-use stream, don't pollute cache); PLAIN stores (match the
// 6.5 TB/s fill-kernel store path — R4 theory test: NT stores were the slack).
__global__ __launch_bounds__(256) void kA_maxcopy(const float* __restrict__ x,
                                                  float* __restrict__ out,
                                                  float* __restrict__ xp) {
    const int slice = blockIdx.x;            // b*D + d
    const int b = slice / D;
    const int d = slice % D;
    const f4* xs = (const f4*)(x + (size_t)slice * FT);
    f4* os = (f4*)(out + ((size_t)(b * OUTC + 2 * Dc + d)) * FT);
    float m = -FLT_MAX;
    // FT/4 = 16384 f4 elements; 256 threads x 8-deep unroll x 8 outer iters
    for (int i0 = threadIdx.x; i0 < FT / 4; i0 += 256 * 8) {
        f4 v[8];
        #pragma unroll
        for (int u = 0; u < 8; ++u)
            v[u] = __builtin_nontemporal_load(&xs[i0 + u * 256]);
        #pragma unroll
        for (int u = 0; u < 8; ++u) {
            os[i0 + u * 256] = v[u];   // plain store
            m = fmaxf(m, fmaxf(fmaxf(v[u].x, v[u].y), fmaxf(v[u].z, v[u].w)));
        }
    }
    // wave (64) reduce then cross-wave via LDS
    for (int off = 32; off; off >>= 1) m = fmaxf(m, __shfl_down(m, off, 64));
    __shared__ float sm[4];
    if ((threadIdx.x & 63) == 0) sm[threadIdx.x >> 6] = m;
    __syncthreads();
    if (threadIdx.x == 0) {
        xp[slice] = fmaxf(fmaxf(sm[0], sm[1]), fmaxf(sm[2], sm[3]));
    }
}

// Kernel B: per (b,c) block — dots, norms, maps, per-(b,p,c) max/argmax
__global__ __launch_bounds__(256) void kB_maps(const float* __restrict__ v0,
                                               const float* __restrict__ v1,
                                               const float* __restrict__ xp,
                                               float* __restrict__ maps,
                                               float* __restrict__ mx,
                                               int* __restrict__ amax) {
    const int bc = blockIdx.x;
    const int b = bc / C, c = bc % C;
    const int tid = threadIdx.x;          // blockDim.x == 256 == Dc

    __shared__ float sxc[Dc], sxo[Dc];
    sxc[tid] = xp[(b * C + c) * Dc + tid];         // xp[b, c, :]
    sxo[tid] = xp[(b * C + (1 - c)) * Dc + tid];   // xp[b, 1-c, :]
    __syncthreads();

    float ec = sxc[tid] * sxc[tid];
    float eo = sxo[tid] * sxo[tid];
    for (int off = 32; off; off >>= 1) {
        ec += __shfl_down(ec, off, 64);
        eo += __shfl_down(eo, off, 64);
    }
    __shared__ float red[8];
    const int lane = tid & 63, wid = tid >> 6;
    if (lane == 0) { red[wid] = ec; red[4 + wid] = eo; }
    __syncthreads();
    __shared__ float s_xn_c, s_xn_o;
    if (tid == 0) {
        s_xn_c = sqrtf(red[0] + red[1] + red[2] + red[3]);  // xn[b,0,c]
        s_xn_o = sqrtf(red[4] + red[5] + red[6] + red[7]);  // xn[b,1,c]
    }
    __syncthreads();
    const float xn_c = s_xn_c, xn_o = s_xn_o;

    float map0 = -FLT_MAX, map1 = -FLT_MAX;
    if (tid < HW) {
        const float* vv = (c == 0 ? v0 : v1) + (size_t)b * Dc * HW;
        float d0 = 0.f, d1 = 0.f, vs = 0.f;
        for (int dc = 0; dc < Dc; ++dc) {
            float v = vv[dc * HW + tid];
            d0 = fmaf(sxc[dc], v, d0);
            d1 = fmaf(sxo[dc], v, d1);
            vs = fmaf(v, v, vs);
        }
        float vn = sqrtf(vs);
        map0 = d0 / fmaxf(xn_c * vn, EPSV);
        map1 = d1 / fmaxf(xn_o * vn, EPSV);
        maps[((b * 2 + 0) * C + c) * HW + tid] = map0;
        maps[((b * 2 + 1) * C + c) * HW + tid] = map1;
    }

    __shared__ float rv[256];
    __shared__ int ri[256];
    for (int p = 0; p < 2; ++p) {
        __syncthreads();
        rv[tid] = (tid < HW) ? (p == 0 ? map0 : map1) : -FLT_MAX;
        ri[tid] = tid;
        __syncthreads();
        for (int s = 128; s; s >>= 1) {
            if (tid < s) {
                float v2 = rv[tid + s]; int i2 = ri[tid + s];
                if (v2 > rv[tid] || (v2 == rv[tid] && i2 < ri[tid])) {
                    rv[tid] = v2; ri[tid] = i2;
                }
            }
            __syncthreads();
        }
        if (tid == 0) {
            mx[(b * 2 + p) * C + c] = rv[0];
            amax[(b * 2 + p) * C + c] = ri[0];
        }
    }
}

// Kernel C: scores, order, match_loss, att_maps, max_ind
__global__ __launch_bounds__(256) void kC_select(const float* __restrict__ maps,
                                                 const float* __restrict__ mx,
                                                 const int* __restrict__ amax,
                                                 float* __restrict__ out,
                                                 int* __restrict__ mind) {
    __shared__ int pbest[B];
    const int tid = threadIdx.x;
    if (tid == 0) {
        float L = 0.f;
        for (int b = 0; b < B; ++b) {
            float s0 = mx[(b * 2 + 0) * C + 0] + mx[(b * 2 + 0) * C + 1];
            float s1 = mx[(b * 2 + 1) * C + 0] + mx[(b * 2 + 1) * C + 1];
            int p = (s1 > s0) ? 1 : 0;   // stable argsort(-scores): tie -> p=0
            pbest[b] = p;
            L += p ? (s0 - s1) : (s1 - s0);
        }
        out[(size_t)B * OUTC * FT] = L / (float)B;
    }
    __syncthreads();
    const size_t att_off = (size_t)B * OUTC * FT + 1;
    for (int i = tid; i < B * C * HW; i += blockDim.x) {
        int b = i / (C * HW);
        int r = i % (C * HW);
        int c = r / HW;
        int hw = r % HW;
        out[att_off + i] = maps[((b * 2 + pbest[b]) * C + c) * HW + hw];
    }
    if (tid < B * C) {
        int b = tid / C, c = tid % C;
        mind[tid] = amax[(b * 2 + pbest[b]) * C + c];
    }
}

// Kernel D: broadcast-fill out[:, 0:2*Dc] — PLAIN stores (fill-kernel path)
__global__ __launch_bounds__(256) void kD_fill(const float* __restrict__ v0,
                                               const float* __restrict__ v1,
                                               const int* __restrict__ mind,
                                               float* __restrict__ out) {
    const int n = blockIdx.x;               // b*(2*Dc) + c*Dc + dc
    const int b = n / (2 * Dc);
    const int r = n % (2 * Dc);
    const int c = r / Dc;
    const int dc = r % Dc;
    const int hw = mind[b * C + c];
    const float* vv = (c == 0 ? v0 : v1);
    const float val = vv[((size_t)(b * Dc + dc)) * HW + hw];
    f4 v4 = {val, val, val, val};
    f4* os = (f4*)(out + ((size_t)(b * OUTC + c * Dc + dc)) * FT);
    for (int i0 = threadIdx.x; i0 < FT / 4; i0 += 256 * 8) {
        #pragma unroll
        for (int u = 0; u < 8; ++u)
            os[i0 + u * 256] = v4;   // plain store
    }
}

extern "C" void kernel_launch(void* const* d_in, const int* in_sizes, int n_in,
                              void* d_out, int out_size, void* d_ws, size_t ws_size,
                              hipStream_t stream) {
    const float* x  = (const float*)d_in[0];
    const float* v0 = (const float*)d_in[1];
    const float* v1 = (const float*)d_in[2];
    float* out = (float*)d_out;
    float* ws = (float*)d_ws;

    float* xp   = ws;                 // 2048
    float* maps = ws + 2048;          // 3136
    float* mx   = ws + 5184;          // 16
    int*   amax = (int*)(ws + 5200);  // 16
    int*   mind = (int*)(ws + 5216);  // 8

    kA_maxcopy<<<B * D, 256, 0, stream>>>(x, out, xp);
    kB_maps<<<B * C, 256, 0, stream>>>(v0, v1, xp, maps, mx, amax);
    kC_select<<<1, 256, 0, stream>>>(maps, mx, amax, out, mind);
    kD_fill<<<B * 2 * Dc, 256, 0, stream>>>(v0, v1, mind, out);
}